// Round 8
// baseline (93.310 us; speedup 1.0000x reference)
//
#include <hip/hip_runtime.h>

// B=2, N=1024, Fin=64, Fout=32 — all fp32.
// Degenerate-score GAT, ONE self-sufficient kernel via linear reassociation:
//   acc_i = (adj_i @ V) @ Wv ;  q1 = K@wk1, wk1 = Wk@a1 (per-block, cheap);
//   e_j periodic with 512 ;  att folds into the same @Wv epilogue.
// 256 blocks x 512 thr; block = (batch b, 8 rows). No inter-block dataflow,
// no grid.sync (measured ~50us, r3/r6), no second graph node (r4->r5: node
// removal saved ~24us).

#define ALPHA 0.01f

__device__ __forceinline__ float leaky(float x){ return x >= 0.f ? x : ALPHA*x; }

__global__ __launch_bounds__(512) void gat_mono(
    const float* __restrict__ inp, const float* __restrict__ kin,
    const float* __restrict__ vin, const float* __restrict__ adj,
    const float* __restrict__ W,   const float* __restrict__ Wk,
    const float* __restrict__ Wv,  const float* __restrict__ a,
    float* __restrict__ out)
{
    __shared__ __align__(16) float adjT[1024*8];   // [j][rr] 32KB
    __shared__ float evals[512];                   // hi only (e_j, period 512)
    __shared__ __align__(16) float wk1[64];
    __shared__ __align__(16) float wk2[64];
    __shared__ __align__(16) float wh[64];
    __shared__ float sp[8][2];                     // lo p-values per row
    __shared__ float smZ[8];
    __shared__ float smT[8*8*64];                  // [js][rr][c] 16KB
    __shared__ float smA[8*64];                    // [js][c]: lo vs / hi R
    __shared__ float smM[8*64];                    // [rr][c]

    const int tid = threadIdx.x;
    const int bid = blockIdx.x;
    const int b   = bid & 1;
    const int it  = bid >> 1;          // 0..127
    const bool hi = (it >= 64);        // rows >= 512
    const int i0  = it*8;

    // ---- S0: stage adjT + weight-derived vectors ----
    {
        int pass = tid >> 8;           // 0,1
        int t256 = tid & 255;
        for (int rr = pass; rr < 8; rr += 2){
            float4 a4 = *(const float4*)(adj + (size_t)(i0+rr)*1024 + t256*4);
            int j = t256*4;
            adjT[(j+0)*8 + rr] = a4.x;
            adjT[(j+1)*8 + rr] = a4.y;
            adjT[(j+2)*8 + rr] = a4.z;
            adjT[(j+3)*8 + rr] = a4.w;
        }
        if (tid < 192){
            int c     = tid & 63;
            int which = tid >> 6;      // 0: wk1, 1: wk2, 2: wh
            const float* Wm = (which == 2) ? W : Wk;
            float acc = 0.f;
            #pragma unroll
            for (int f = 0; f < 32; f++){
                float av = (which == 0) ? a[f] : (which == 1) ? a[32+f]
                                               : (a[f] + a[32+f]);
                acc += Wm[c*32+f] * av;
            }
            if (which == 0) wk1[c] = acc;
            else if (which == 1) wk2[c] = acc;
            else wh[c] = acc;
        }
    }
    __syncthreads();

    // ---- S1: hi -> e-values + Z ; lo -> p-values ----
    if (hi){
        int jq = tid;                                   // pair index 0..511
        const float* kr = kin + ((size_t)b*1024 + 2*jq)*64;
        float d1 = 0.f, d2 = 0.f;
        #pragma unroll
        for (int c4 = 0; c4 < 64; c4 += 4){
            float4 k0 = *(const float4*)(kr + c4);
            float4 k1 = *(const float4*)(kr + 64 + c4);
            float4 w1 = *(const float4*)(&wk1[c4]);
            float4 w2 = *(const float4*)(&wk2[c4]);
            d1 += k0.x*w1.x + k0.y*w1.y + k0.z*w1.z + k0.w*w1.w;
            d2 += k1.x*w2.x + k1.y*w2.y + k1.z*w2.z + k1.w*w2.w;
        }
        float ev = __expf(leaky(d1 + d2));
        evals[jq] = ev;
        float z = ev;
        #pragma unroll
        for (int m = 32; m; m >>= 1) z += __shfl_xor(z, m);
        if ((tid & 63) == 0) smZ[tid >> 6] = z;
    } else {
        if (tid < 16){
            int rr = tid >> 1, dlt = tid & 1;
            const float* xr = inp + ((size_t)b*1024 + 2*(i0+rr) + dlt)*64;
            float s = 0.f;
            #pragma unroll
            for (int c = 0; c < 64; c++) s += xr[c]*wh[c];
            sp[rr][dlt] = s;
        }
    }
    __syncthreads();

    // ---- S2: T-pass.  thread = (c = tid&63, js = tid>>6); 128 j per thread.
    {
        int c  = tid & 63;
        int js = tid >> 6;
        int j0 = js*128;
        const float* vb = vin + (size_t)b*65536 + c;
        float T0=0,T1=0,T2=0,T3=0,T4=0,T5=0,T6=0,T7=0, aux=0;
        if (hi){
            #pragma unroll 4
            for (int j = j0; j < j0+128; j++){
                float val = vb[(size_t)j*64];
                float4 A0 = *(const float4*)(&adjT[j*8]);
                float4 A1 = *(const float4*)(&adjT[j*8+4]);
                float ev  = evals[j & 511];
                T0 += A0.x*val; T1 += A0.y*val; T2 += A0.z*val; T3 += A0.w*val;
                T4 += A1.x*val; T5 += A1.y*val; T6 += A1.z*val; T7 += A1.w*val;
                aux += ev*val;
            }
        } else {
            #pragma unroll 4
            for (int j = j0; j < j0+128; j++){
                float val = vb[(size_t)j*64];
                float4 A0 = *(const float4*)(&adjT[j*8]);
                float4 A1 = *(const float4*)(&adjT[j*8+4]);
                T0 += A0.x*val; T1 += A0.y*val; T2 += A0.z*val; T3 += A0.w*val;
                T4 += A1.x*val; T5 += A1.y*val; T6 += A1.z*val; T7 += A1.w*val;
                aux += val;
            }
        }
        smT[(js*8+0)*64+c] = T0; smT[(js*8+1)*64+c] = T1;
        smT[(js*8+2)*64+c] = T2; smT[(js*8+3)*64+c] = T3;
        smT[(js*8+4)*64+c] = T4; smT[(js*8+5)*64+c] = T5;
        smT[(js*8+6)*64+c] = T6; smT[(js*8+7)*64+c] = T7;
        smA[js*64+c] = aux;
    }
    __syncthreads();

    // ---- S3: reduce js + fold attention into M[rr][c] ----
    {
        int c2  = tid & 63;
        int rr2 = tid >> 6;
        float M = 0.f;
        #pragma unroll
        for (int js2 = 0; js2 < 8; js2++) M += smT[(js2*8+rr2)*64 + c2];
        if (hi){
            float Z = 2.f*(smZ[0]+smZ[1]+smZ[2]+smZ[3]+smZ[4]+smZ[5]+smZ[6]+smZ[7]);
            float R = 0.f;
            #pragma unroll
            for (int js2 = 0; js2 < 8; js2++) R += smA[js2*64 + c2];
            M += R / Z;
        } else {
            float vlo = smA[0*64+c2] + smA[1*64+c2] + smA[2*64+c2] + smA[3*64+c2];
            float vhi = smA[4*64+c2] + smA[5*64+c2] + smA[6*64+c2] + smA[7*64+c2];
            float s0 = leaky(sp[rr2][0]);
            float s1 = leaky(sp[rr2][1]);
            float e0 = __expf(s0), e1 = __expf(s1);
            float inv = 1.f/(512.f*(e0 + e1));
            M += (e0*vlo + e1*vhi)*inv;
        }
        smM[rr2*64 + c2] = M;
    }
    __syncthreads();

    // ---- S4: out[rr][f] = leaky(0.5 * M[rr][:] @ Wv[:,f]) ----
    {
        int f2   = tid & 31;
        int half = (tid >> 5) & 1;
        int rr3  = tid >> 6;
        int cb   = half*32;
        const float* wv = Wv + f2;
        float o = 0.f;
        #pragma unroll 8
        for (int cc = 0; cc < 32; cc++){
            o += smM[rr3*64 + cb + cc] * wv[(cb + cc)*32];
        }
        o += __shfl_xor(o, 32);
        if (half == 0){
            out[((size_t)b*1024 + i0 + rr3)*32 + f2] = leaky(0.5f*o);
        }
    }
}

extern "C" void kernel_launch(void* const* d_in, const int* in_sizes, int n_in,
                              void* d_out, int out_size, void* d_ws, size_t ws_size,
                              hipStream_t stream)
{
    const float* inp = (const float*)d_in[0];
    const float* kin = (const float*)d_in[1];
    const float* vin = (const float*)d_in[2];
    const float* adj = (const float*)d_in[3];
    const float* W   = (const float*)d_in[4];
    const float* Wk  = (const float*)d_in[5];
    const float* Wv  = (const float*)d_in[6];
    const float* a   = (const float*)d_in[7];
    float* out = (float*)d_out;
    (void)in_sizes; (void)n_in; (void)out_size; (void)d_ws; (void)ws_size;

    hipLaunchKernelGGL(gat_mono, dim3(256), dim3(512), 0, stream,
                       inp, kin, vin, adj, W, Wk, Wv, a, out);
}

// Round 9
// 87.342 us; speedup vs baseline: 1.0683x; 1.0683x over previous
//
#include <hip/hip_runtime.h>

// B=2, N=1024, Fin=64, Fout=32 — all fp32.
// Degenerate-score GAT, 2 kernels (round-5 structure, block-specialized K2):
//   K1 k_proj : projections -> vv (j-major [b][j][f]), p, q1, q2
//   K2 k_fused: adj.vv dot + fused softmax reductions + epilogue, with
//     block-uniform specialization:
//       it<128  (rows i<512) : acc + vs only — no e staging, no barrier#1
//       it>=128 (rows i>=512): acc + racc + Z only — no vs
// Structure notes (measured this session):
//   - cooperative grid.sync ~50us (r3/r6) — never use here.
//   - single mono kernel w/ reassociation: +6.5us vs this (r8) — phase
//     serialization + scalar stride-64 loads beat the node-gap saving.
//   - 3-node pipeline: +24us vs 2-node (r4->r5).

#define ALPHA 0.01f

__device__ __forceinline__ float leaky(float x){ return x >= 0.f ? x : ALPHA*x; }

// ---------------- K1: projections + row scalars -------------------------
// 512 blocks x 256 thr; 4 rows/block; wave = 1 row; lane-halves split c.
__global__ __launch_bounds__(256) void k_proj(
    const float* __restrict__ inp, const float* __restrict__ kin,
    const float* __restrict__ vin, const float* __restrict__ W,
    const float* __restrict__ Wk,  const float* __restrict__ Wv,
    const float* __restrict__ a,
    float* __restrict__ vv, float* __restrict__ p,
    float* __restrict__ q1, float* __restrict__ q2)
{
    int tid  = threadIdx.x;
    int lane = tid & 63;
    int f    = lane & 31;
    int h    = lane >> 5;          // c-half selector
    int rl   = tid >> 6;           // 0..3
    int row  = blockIdx.x*4 + rl;  // 0..2047
    const float* xr = inp + row*64 + h*32;
    const float* kr = kin + row*64 + h*32;
    const float* vr = vin + row*64 + h*32;
    const float* Wb  = W  + (h*32)*32 + f;
    const float* Wkb = Wk + (h*32)*32 + f;
    const float* Wvb = Wv + (h*32)*32 + f;
    float ha = 0.f, ka = 0.f, va = 0.f;
    #pragma unroll
    for (int c = 0; c < 32; c++){
        float x = xr[c], k = kr[c], v = vr[c];
        ha += x * Wb [c*32];
        ka += k * Wkb[c*32];
        va += v * Wvb[c*32];
    }
    ha += __shfl_xor(ha, 32);
    ka += __shfl_xor(ka, 32);
    va += __shfl_xor(va, 32);
    if (h == 0) vv[row*32 + f] = va;        // j-major layout
    float a1 = a[f], a2 = a[32+f];
    float pv  = ha*(a1+a2);
    float q1v = ka*a1;
    float q2v = ka*a2;
    #pragma unroll
    for (int m = 16; m; m >>= 1){
        pv  += __shfl_xor(pv , m);
        q1v += __shfl_xor(q1v, m);
        q2v += __shfl_xor(q2v, m);
    }
    if (lane == 0){ p[row] = pv; q1[row] = q1v; q2[row] = q2v; }
}

// ---------------- K2: fused softmax + adj@vv + epilogue -----------------
// 512 blocks x 256 thr. block = (batch b, 4 rows). thread = (o, rr, js):
//   o  = tid&7        feature quad (f = o*4..o*4+3)
//   rr = (tid>>3)&3   row within block
//   js = tid>>5       j-slice of 128 (waves 0-1: j<512, waves 2-3: j>=512)
__global__ __launch_bounds__(256) void k_fused(
    const float* __restrict__ adj, const float* __restrict__ vv,
    const float* __restrict__ p,   const float* __restrict__ q1,
    const float* __restrict__ q2,  float* __restrict__ out)
{
    __shared__ float e[1024];            // hi-blocks only
    __shared__ float accred[4][4][32];   // [wave][row][feature]
    __shared__ float xred[4][32];        // lo: vs partials / hi: racc partials
    __shared__ float zred[4];            // hi-blocks only

    int tid = threadIdx.x;
    int b   = blockIdx.x & 1;
    int it  = blockIdx.x >> 1;        // 0..255
    int o   = tid & 7;
    int rr  = (tid >> 3) & 3;
    int js  = tid >> 5;               // 0..7
    int w   = tid >> 6;               // wave 0..3
    int i   = it*4 + rr;
    bool hi = (it >= 128);            // block-uniform: rows i >= 512

    const float4* ap = (const float4*)(adj + i*1024 + js*128);
    const float*  vb = vv + b*32768 + js*128*32 + o*4;
    float4 acc = make_float4(0.f,0.f,0.f,0.f);
    float4 aux = make_float4(0.f,0.f,0.f,0.f);   // lo: vs / hi: racc

    if (hi){
        // ---- stage e[1024] + Z (scores ~|2|, exp w/o max-sub safe) ----
        const float* q1b = q1 + b*1024;
        const float* q2b = q2 + b*1024;
        float zsum = 0.f;
        #pragma unroll
        for (int t = 0; t < 4; t++){
            int j  = tid*4 + t;
            float s = leaky(q1b[(2*j) & 1023] + q2b[(2*j+1) & 1023]);
            float ev = __expf(s);
            e[j] = ev;
            zsum += ev;
        }
        #pragma unroll
        for (int m = 32; m; m >>= 1) zsum += __shfl_xor(zsum, m);
        if ((tid & 63) == 0) zred[w] = zsum;
        __syncthreads();

        const float4* ep = (const float4*)(e + js*128);
        #pragma unroll 4
        for (int m = 0; m < 32; m++){
            float4 a4 = ap[m];
            float4 e4 = ep[m];
            const float* v0p = vb + m*128;
            float4 v0 = *(const float4*)(v0p);
            float4 v1 = *(const float4*)(v0p + 32);
            float4 v2 = *(const float4*)(v0p + 64);
            float4 v3 = *(const float4*)(v0p + 96);
            acc.x += a4.x*v0.x; acc.y += a4.x*v0.y; acc.z += a4.x*v0.z; acc.w += a4.x*v0.w;
            acc.x += a4.y*v1.x; acc.y += a4.y*v1.y; acc.z += a4.y*v1.z; acc.w += a4.y*v1.w;
            acc.x += a4.z*v2.x; acc.y += a4.z*v2.y; acc.z += a4.z*v2.z; acc.w += a4.z*v2.w;
            acc.x += a4.w*v3.x; acc.y += a4.w*v3.y; acc.z += a4.w*v3.z; acc.w += a4.w*v3.w;
            aux.x += e4.x*v0.x; aux.y += e4.x*v0.y; aux.z += e4.x*v0.z; aux.w += e4.x*v0.w;
            aux.x += e4.y*v1.x; aux.y += e4.y*v1.y; aux.z += e4.y*v1.z; aux.w += e4.y*v1.w;
            aux.x += e4.z*v2.x; aux.y += e4.z*v2.y; aux.z += e4.z*v2.z; aux.w += e4.z*v2.w;
            aux.x += e4.w*v3.x; aux.y += e4.w*v3.y; aux.z += e4.w*v3.z; aux.w += e4.w*v3.w;
        }
    } else {
        // ---- lo: acc + column-sums of vv only ----
        #pragma unroll 4
        for (int m = 0; m < 32; m++){
            float4 a4 = ap[m];
            const float* v0p = vb + m*128;
            float4 v0 = *(const float4*)(v0p);
            float4 v1 = *(const float4*)(v0p + 32);
            float4 v2 = *(const float4*)(v0p + 64);
            float4 v3 = *(const float4*)(v0p + 96);
            acc.x += a4.x*v0.x; acc.y += a4.x*v0.y; acc.z += a4.x*v0.z; acc.w += a4.x*v0.w;
            acc.x += a4.y*v1.x; acc.y += a4.y*v1.y; acc.z += a4.y*v1.z; acc.w += a4.y*v1.w;
            acc.x += a4.z*v2.x; acc.y += a4.z*v2.y; acc.z += a4.z*v2.z; acc.w += a4.z*v2.w;
            acc.x += a4.w*v3.x; acc.y += a4.w*v3.y; acc.z += a4.w*v3.z; acc.w += a4.w*v3.w;
            aux.x += v0.x + v1.x + v2.x + v3.x;
            aux.y += v0.y + v1.y + v2.y + v3.y;
            aux.z += v0.z + v1.z + v2.z + v3.z;
            aux.w += v0.w + v1.w + v2.w + v3.w;
        }
    }

    // combine js pairs within wave (lane ^ 32)
    acc.x += __shfl_xor(acc.x, 32); acc.y += __shfl_xor(acc.y, 32);
    acc.z += __shfl_xor(acc.z, 32); acc.w += __shfl_xor(acc.w, 32);
    aux.x += __shfl_xor(aux.x, 32); aux.y += __shfl_xor(aux.y, 32);
    aux.z += __shfl_xor(aux.z, 32); aux.w += __shfl_xor(aux.w, 32);
    if ((tid & 32) == 0){
        accred[w][rr][o*4+0] = acc.x;
        accred[w][rr][o*4+1] = acc.y;
        accred[w][rr][o*4+2] = acc.z;
        accred[w][rr][o*4+3] = acc.w;
        if (rr == 0){
            xred[w][o*4+0] = aux.x; xred[w][o*4+1] = aux.y;
            xred[w][o*4+2] = aux.z; xred[w][o*4+3] = aux.w;
        }
    }
    __syncthreads();

    // ---- epilogue: 128 threads = (row rr2, feature f) ----
    if (tid < 128){
        int rr2 = tid >> 5, f = tid & 31;
        float accsum = accred[0][rr2][f] + accred[1][rr2][f]
                     + accred[2][rr2][f] + accred[3][rr2][f];
        int i2 = it*4 + rr2;
        float att;
        if (!hi){
            float vlo = xred[0][f] + xred[1][f];   // j <  512
            float vhi = xred[2][f] + xred[3][f];   // j >= 512
            float s0 = leaky(p[b*1024 + 2*i2]);
            float s1 = leaky(p[b*1024 + 2*i2 + 1]);
            float e0 = __expf(s0), e1 = __expf(s1);
            att = (e0*vlo + e1*vhi) / (512.f*(e0 + e1));
        } else {
            float rsum = xred[0][f] + xred[1][f] + xred[2][f] + xred[3][f];
            float Z = zred[0] + zred[1] + zred[2] + zred[3];
            att = rsum / Z;
        }
        out[(b*1024 + i2)*32 + f] = leaky(0.5f*(att + accsum));
    }
}

extern "C" void kernel_launch(void* const* d_in, const int* in_sizes, int n_in,
                              void* d_out, int out_size, void* d_ws, size_t ws_size,
                              hipStream_t stream)
{
    const float* inp = (const float*)d_in[0];
    const float* kin = (const float*)d_in[1];
    const float* vin = (const float*)d_in[2];
    const float* adj = (const float*)d_in[3];
    const float* W   = (const float*)d_in[4];
    const float* Wk  = (const float*)d_in[5];
    const float* Wv  = (const float*)d_in[6];
    const float* a   = (const float*)d_in[7];
    float* out = (float*)d_out;

    float* ws  = (float*)d_ws;
    float* vv  = ws;            // 65536 floats, [b][j][f]
    float* p   = ws + 65536;    // 2048
    float* q1  = ws + 67584;    // 2048
    float* q2  = ws + 69632;    // 2048
    (void)in_sizes; (void)n_in; (void)out_size; (void)ws_size;

    hipLaunchKernelGGL(k_proj, dim3(512), dim3(256), 0, stream,
                       inp, kin, vin, W, Wk, Wv, a, vv, p, q1, q2);
    hipLaunchKernelGGL(k_fused, dim3(512), dim3(256), 0, stream,
                       adj, vv, p, q1, q2, out);
}